// Round 11
// baseline (2706.599 us; speedup 1.0000x reference)
//
#include <hip/hip_runtime.h>
#include <hip/hip_bf16.h>

// Sizes fixed by the problem
#define BB 128
#define SS 1024
#define FF 512
#define HH 128
#define G3 384   // 3*H

typedef __attribute__((ext_vector_type(8))) short bf16x8;
typedef __attribute__((ext_vector_type(4))) float f32x4;
typedef _Float16 half2_t __attribute__((ext_vector_type(2)));

// ---------------------------------------------------------------------------
// lengths: len[b] = #rows t with sum_f x[b,t,f] != 0
// ---------------------------------------------------------------------------
__global__ void zero_len_kernel(int* len) { len[threadIdx.x] = 0; }

__global__ void lengths_kernel(const float* __restrict__ x, int* __restrict__ len) {
    int wave = threadIdx.x >> 6;
    int lane = threadIdx.x & 63;
    long row = (long)blockIdx.x * 4 + wave;   // 0 .. 131071
    const float4* p = (const float4*)&x[row * FF + lane * 8];
    float4 v0 = p[0], v1 = p[1];
    float s = v0.x + v0.y + v0.z + v0.w + v1.x + v1.y + v1.z + v1.w;
    #pragma unroll
    for (int off = 32; off > 0; off >>= 1) s += __shfl_down(s, off, 64);
    if (lane == 0 && s != 0.0f) atomicAdd(&len[row >> 10], 1);
}

__global__ void rank_kernel(const int* __restrict__ len, int* __restrict__ rank) {
    int i = threadIdx.x;
    int li = len[i];
    int r = 0;
    for (int jj = 0; jj < BB; jj++) {
        int lj = len[jj];
        if (lj > li || (lj == li && jj < i)) r++;
    }
    rank[i] = r;
}

// ---------------------------------------------------------------------------
// bf16 split helpers (RTN-even rounding; no NaN/inf in this data)
// ---------------------------------------------------------------------------
__device__ __forceinline__ short bf_hi(float w, float& hf) {
    unsigned u = __builtin_bit_cast(unsigned, w);
    unsigned r = (u + 0x7FFFu + ((u >> 16) & 1u)) & 0xFFFF0000u;
    hf = __builtin_bit_cast(float, r);
    return (short)(r >> 16);
}
__device__ __forceinline__ short bf_rn(float w) {
    unsigned u = __builtin_bit_cast(unsigned, w);
    unsigned r = u + 0x7FFFu + ((u >> 16) & 1u);
    return (short)(r >> 16);
}

// ---------------------------------------------------------------------------
// Split-bf16 MFMA GEMM: C[M,N] = A[M,K] @ W[N,K]^T + bias[N]
// (unchanged from round 6; 3-pass hh+hl+lh split -> fp32-grade accuracy)
// ---------------------------------------------------------------------------
__global__ __launch_bounds__(256) void gemm_mfma(
    const float* __restrict__ A, const float* __restrict__ W,
    const float* __restrict__ bias, float* __restrict__ C,
    int M, int N, int K)
{
    const int tid  = threadIdx.x;
    const int wvid = tid >> 6;
    const int lane = tid & 63;
    const int m0   = blockIdx.x * 64 + wvid * 16;
    const int n0   = blockIdx.y * 128;
    const int KS   = K >> 5;

    __shared__ __align__(16) short sh[2][8][64][8];   // 16KB

    f32x4 acc[8];
    #pragma unroll
    for (int i = 0; i < 8; i++) acc[i] = (f32x4){0.f, 0.f, 0.f, 0.f};

    const int arow = m0 + (lane & 15);
    const int koff = (lane >> 4) << 3;

    for (int ks = 0; ks < KS; ks++) {
        __syncthreads();
        #pragma unroll
        for (int i = 0; i < 2; i++) {
            int p  = tid + i * 256;
            int nt = p >> 6, ln = p & 63;
            const float* src = &W[(size_t)(n0 + nt * 16 + (ln & 15)) * K
                                  + ks * 32 + ((ln >> 4) << 3)];
            float w8[8];
            *(float4*)&w8[0] = *(const float4*)&src[0];
            *(float4*)&w8[4] = *(const float4*)&src[4];
            short hi8[8], lo8[8];
            #pragma unroll
            for (int e = 0; e < 8; e++) {
                float hf; hi8[e] = bf_hi(w8[e], hf);
                lo8[e] = bf_rn(w8[e] - hf);
            }
            *(bf16x8*)&sh[0][nt][ln][0] = *(bf16x8*)hi8;
            *(bf16x8*)&sh[1][nt][ln][0] = *(bf16x8*)lo8;
        }
        const float* ap = &A[(size_t)arow * K + ks * 32 + koff];
        float av[8];
        *(float4*)&av[0] = *(const float4*)&ap[0];
        *(float4*)&av[4] = *(const float4*)&ap[4];
        short ah[8], al[8];
        #pragma unroll
        for (int e = 0; e < 8; e++) {
            float hf; ah[e] = bf_hi(av[e], hf);
            al[e] = bf_rn(av[e] - hf);
        }
        bf16x8 ahi = *(bf16x8*)ah, alo = *(bf16x8*)al;
        __syncthreads();
        #pragma unroll
        for (int nt = 0; nt < 8; nt++) {
            bf16x8 bhi = *(bf16x8*)&sh[0][nt][lane][0];
            bf16x8 blo = *(bf16x8*)&sh[1][nt][lane][0];
            acc[nt] = __builtin_amdgcn_mfma_f32_16x16x32_bf16(ahi, bhi, acc[nt], 0, 0, 0);
            acc[nt] = __builtin_amdgcn_mfma_f32_16x16x32_bf16(ahi, blo, acc[nt], 0, 0, 0);
            acc[nt] = __builtin_amdgcn_mfma_f32_16x16x32_bf16(alo, bhi, acc[nt], 0, 0, 0);
        }
    }
    const int crow = m0 + ((lane >> 4) << 2);
    const int ccol = n0 + (lane & 15);
    #pragma unroll
    for (int nt = 0; nt < 8; nt++) {
        int col = ccol + nt * 16;
        float bv = bias[col];
        #pragma unroll
        for (int r = 0; r < 4; r++)
            C[(size_t)(crow + r) * N + col] = acc[nt][r] + bv;
    }
}

// ---------------------------------------------------------------------------
// f16 helpers
// ---------------------------------------------------------------------------
__device__ __forceinline__ float fast_sigmoid(float x) {
    return __builtin_amdgcn_rcpf(1.0f + __expf(-x));
}
__device__ __forceinline__ float fast_tanh(float x) {
    return 1.0f - 2.0f * __builtin_amdgcn_rcpf(1.0f + __expf(2.0f * x));
}
__device__ __forceinline__ half2_t bc16(unsigned u) {
    return __builtin_bit_cast(half2_t, u);
}
__device__ __forceinline__ unsigned pk16(float x, float y) {
    half2_t h; h[0] = (_Float16)x; h[1] = (_Float16)y;
    return __builtin_bit_cast(unsigned, h);
}
__device__ __forceinline__ float fdot2_(half2_t a, half2_t b, float c) {
#if __has_builtin(__builtin_amdgcn_fdot2)
    return __builtin_amdgcn_fdot2(a, b, c, false);
#else
    return c + (float)a[0] * (float)b[0] + (float)a[1] * (float)b[1];
#endif
}

// ---------------------------------------------------------------------------
// GRU recurrence, v11: weights in PHYSICAL AGPRs a0..a95.
// r3-r10 verdict: every virtual-register strategy converges to "re-stream
// 96-192KB of weights per step" (scratch/L2 or LDS, both ~1500-1800 cy/step).
// The allocator spills/remats virtual regs no matter what; LDS ds_read_b128
// pipe is ~85 B/cy. Physical AGPRs named in inline asm are OUTSIDE the
// allocator's reach: written once (v_accvgpr_write_b32, clobbers declared ->
// .agpr_count=96), read each step as 1-cy register ops. gru_rec has no MFMA
// and ~70 VGPRs, so a0..a95 are otherwise untouched.
// Geometry: 256 thr; thread (j2=tid>>2, kq=tid&3) owns rows {2j2,2j2+1} x
// 3 gates x k-slice [kq*32..+32) = 96 f16-pair words. h: 4 x ds_read_b128.
// ---------------------------------------------------------------------------
#define AW(N) asm volatile("v_accvgpr_write_b32 a" #N ", %0" :: "v"(wt[(N) & 15]) : "a" #N)
#define DOT(N, ACC) do { unsigned _w; \
    asm volatile("v_accvgpr_read_b32 %0, a" #N : "=v"(_w)); \
    ACC = fdot2_(bc16(_w), bc16(hw[(N) & 15]), ACC); } while (0)

template<int FINAL>
__global__ __launch_bounds__(256, 1) void gru_rec(
    const float* __restrict__ xg,    // [B,S,3H]
    const float* __restrict__ Whh,   // [3H,H]
    const float* __restrict__ bhh,   // [3H]
    float* __restrict__ h_out,       // [B,S,H] (FINAL=0) or [B,H] (FINAL=1)
    const int* __restrict__ len,
    const int* __restrict__ rank)
{
    const int b   = blockIdx.x;
    const int tid = threadIdx.x;
    const int j2  = tid >> 2;     // 0..63 -> rows 2*j2, 2*j2+1
    const int kq  = tid & 3;      // K-quarter (32 elems = 16 f16 pairs)
    const int j0  = 2 * j2, j1 = 2 * j2 + 1;

    __shared__ __align__(16) unsigned h16u[2][64];   // h as f16 pairs
    __shared__ __align__(16) float    h32[2][HH];    // h fp32 for writeout

    // ---- one-time: pack weights to f16 pairs, store in physical a0..a95 ----
    unsigned wt[16];
    { const float* wr = &Whh[(size_t)(0 * HH + j0) * HH + kq * 32];
      #pragma unroll
      for (int m = 0; m < 16; m++) wt[m] = pk16(wr[2*m], wr[2*m+1]); }
    AW(0);  AW(1);  AW(2);  AW(3);  AW(4);  AW(5);  AW(6);  AW(7);
    AW(8);  AW(9);  AW(10); AW(11); AW(12); AW(13); AW(14); AW(15);
    { const float* wr = &Whh[(size_t)(1 * HH + j0) * HH + kq * 32];
      #pragma unroll
      for (int m = 0; m < 16; m++) wt[m] = pk16(wr[2*m], wr[2*m+1]); }
    AW(16); AW(17); AW(18); AW(19); AW(20); AW(21); AW(22); AW(23);
    AW(24); AW(25); AW(26); AW(27); AW(28); AW(29); AW(30); AW(31);
    { const float* wr = &Whh[(size_t)(2 * HH + j0) * HH + kq * 32];
      #pragma unroll
      for (int m = 0; m < 16; m++) wt[m] = pk16(wr[2*m], wr[2*m+1]); }
    AW(32); AW(33); AW(34); AW(35); AW(36); AW(37); AW(38); AW(39);
    AW(40); AW(41); AW(42); AW(43); AW(44); AW(45); AW(46); AW(47);
    { const float* wr = &Whh[(size_t)(0 * HH + j1) * HH + kq * 32];
      #pragma unroll
      for (int m = 0; m < 16; m++) wt[m] = pk16(wr[2*m], wr[2*m+1]); }
    AW(48); AW(49); AW(50); AW(51); AW(52); AW(53); AW(54); AW(55);
    AW(56); AW(57); AW(58); AW(59); AW(60); AW(61); AW(62); AW(63);
    { const float* wr = &Whh[(size_t)(1 * HH + j1) * HH + kq * 32];
      #pragma unroll
      for (int m = 0; m < 16; m++) wt[m] = pk16(wr[2*m], wr[2*m+1]); }
    AW(64); AW(65); AW(66); AW(67); AW(68); AW(69); AW(70); AW(71);
    AW(72); AW(73); AW(74); AW(75); AW(76); AW(77); AW(78); AW(79);
    { const float* wr = &Whh[(size_t)(2 * HH + j1) * HH + kq * 32];
      #pragma unroll
      for (int m = 0; m < 16; m++) wt[m] = pk16(wr[2*m], wr[2*m+1]); }
    AW(80); AW(81); AW(82); AW(83); AW(84); AW(85); AW(86); AW(87);
    AW(88); AW(89); AW(90); AW(91); AW(92); AW(93); AW(94); AW(95);

    float2 brv = {0.f, 0.f}, bzv = {0.f, 0.f}, bnv = {0.f, 0.f};
    if (kq == 0) {
        brv = *(const float2*)&bhh[j0];
        bzv = *(const float2*)&bhh[HH + j0];
        bnv = *(const float2*)&bhh[2 * HH + j0];
    }
    const float* xgb = xg + (size_t)b * SS * G3;

    if (tid < 64)  { h16u[0][tid] = 0u; }
    if (tid < 128) { h32[0][tid] = 0.f; }
    float hprev0 = 0.f, hprev1 = 0.f, osum0 = 0.f, osum1 = 0.f;
    const int L = FINAL ? len[b] : 0;

    float2 xrv = {0,0}, xzv = {0,0}, xnv = {0,0};
    if (kq == 0) {
        xrv = *(const float2*)&xgb[j0];
        xzv = *(const float2*)&xgb[HH + j0];
        xnv = *(const float2*)&xgb[2 * HH + j0];
    }
    __syncthreads();

    for (int t = 0; t < SS; t++) {
        const int cb = t & 1, nb = (t + 1) & 1;

        // lagged coalesced global write of h_{t-1}
        if (!FINAL && t > 0 && tid >= 64 && tid < 96) {
            int c = tid - 64;
            float4 hv = ((const float4*)h32[cb])[c];
            *(float4*)&h_out[((size_t)b * SS + (t - 1)) * HH + c * 4] = hv;
        }
        // prefetch xg for t+1
        float2 nxr = {0,0}, nxz = {0,0}, nxn = {0,0};
        if (kq == 0 && t + 1 < SS) {
            const float* p = xgb + (size_t)(t + 1) * G3;
            nxr = *(const float2*)&p[j0];
            nxz = *(const float2*)&p[HH + j0];
            nxn = *(const float2*)&p[2 * HH + j0];
        }
        // h slice: 32 f16 = 4 x b128 (2-way bank alias across kq: free)
        const uint4* hp = (const uint4*)&h16u[cb][kq * 16];
        uint4 q0 = hp[0], q1 = hp[1], q2 = hp[2], q3 = hp[3];
        unsigned hw[16] = {q0.x,q0.y,q0.z,q0.w, q1.x,q1.y,q1.z,q1.w,
                           q2.x,q2.y,q2.z,q2.w, q3.x,q3.y,q3.z,q3.w};

        float rA, rB, zA, zB, nA, nB;
        // row j0
        rA = 0.f; rB = 0.f;
        DOT(0,rA);  DOT(1,rB);  DOT(2,rA);  DOT(3,rB);
        DOT(4,rA);  DOT(5,rB);  DOT(6,rA);  DOT(7,rB);
        DOT(8,rA);  DOT(9,rB);  DOT(10,rA); DOT(11,rB);
        DOT(12,rA); DOT(13,rB); DOT(14,rA); DOT(15,rB);
        zA = 0.f; zB = 0.f;
        DOT(16,zA); DOT(17,zB); DOT(18,zA); DOT(19,zB);
        DOT(20,zA); DOT(21,zB); DOT(22,zA); DOT(23,zB);
        DOT(24,zA); DOT(25,zB); DOT(26,zA); DOT(27,zB);
        DOT(28,zA); DOT(29,zB); DOT(30,zA); DOT(31,zB);
        nA = 0.f; nB = 0.f;
        DOT(32,nA); DOT(33,nB); DOT(34,nA); DOT(35,nB);
        DOT(36,nA); DOT(37,nB); DOT(38,nA); DOT(39,nB);
        DOT(40,nA); DOT(41,nB); DOT(42,nA); DOT(43,nB);
        DOT(44,nA); DOT(45,nB); DOT(46,nA); DOT(47,nB);
        float sr0 = rA + rB, sz0 = zA + zB, sn0 = nA + nB;
        // row j1
        rA = 0.f; rB = 0.f;
        DOT(48,rA); DOT(49,rB); DOT(50,rA); DOT(51,rB);
        DOT(52,rA); DOT(53,rB); DOT(54,rA); DOT(55,rB);
        DOT(56,rA); DOT(57,rB); DOT(58,rA); DOT(59,rB);
        DOT(60,rA); DOT(61,rB); DOT(62,rA); DOT(63,rB);
        zA = 0.f; zB = 0.f;
        DOT(64,zA); DOT(65,zB); DOT(66,zA); DOT(67,zB);
        DOT(68,zA); DOT(69,zB); DOT(70,zA); DOT(71,zB);
        DOT(72,zA); DOT(73,zB); DOT(74,zA); DOT(75,zB);
        DOT(76,zA); DOT(77,zB); DOT(78,zA); DOT(79,zB);
        nA = 0.f; nB = 0.f;
        DOT(80,nA); DOT(81,nB); DOT(82,nA); DOT(83,nB);
        DOT(84,nA); DOT(85,nB); DOT(86,nA); DOT(87,nB);
        DOT(88,nA); DOT(89,nB); DOT(90,nA); DOT(91,nB);
        DOT(92,nA); DOT(93,nB); DOT(94,nA); DOT(95,nB);
        float sr1 = rA + rB, sz1 = zA + zB, sn1 = nA + nB;

        // reduce over kq (lanes 1,2 apart in same wave)
        sr0 += __shfl_xor(sr0, 1, 64); sr0 += __shfl_xor(sr0, 2, 64);
        sz0 += __shfl_xor(sz0, 1, 64); sz0 += __shfl_xor(sz0, 2, 64);
        sn0 += __shfl_xor(sn0, 1, 64); sn0 += __shfl_xor(sn0, 2, 64);
        sr1 += __shfl_xor(sr1, 1, 64); sr1 += __shfl_xor(sr1, 2, 64);
        sz1 += __shfl_xor(sz1, 1, 64); sz1 += __shfl_xor(sz1, 2, 64);
        sn1 += __shfl_xor(sn1, 1, 64); sn1 += __shfl_xor(sn1, 2, 64);

        if (kq == 0) {
            float r0 = fast_sigmoid(xrv.x + sr0 + brv.x);
            float z0 = fast_sigmoid(xzv.x + sz0 + bzv.x);
            float n0 = fast_tanh(xnv.x + r0 * (sn0 + bnv.x));
            float h0 = (1.0f - z0) * n0 + z0 * hprev0;
            float r1 = fast_sigmoid(xrv.y + sr1 + brv.y);
            float z1 = fast_sigmoid(xzv.y + sz1 + bzv.y);
            float n1 = fast_tanh(xnv.y + r1 * (sn1 + bnv.y));
            float h1 = (1.0f - z1) * n1 + z1 * hprev1;
            hprev0 = h0; hprev1 = h1;
            h16u[nb][j2] = pk16(h0, h1);
            *(float2*)&h32[nb][j0] = make_float2(h0, h1);
            if (FINAL) { if (t < L) { osum0 += h0; osum1 += h1; } }
        }
        xrv = nxr; xzv = nxz; xnv = nxn;
        __syncthreads();
    }
    if (!FINAL && tid >= 64 && tid < 96) {
        int c = tid - 64;
        float4 hv = ((const float4*)h32[SS & 1])[c];
        *(float4*)&h_out[((size_t)b * SS + (SS - 1)) * HH + c * 4] = hv;
    }
    if (FINAL && kq == 0) {
        float2 o = make_float2(osum0 * (1.0f / (float)SS), osum1 * (1.0f / (float)SS));
        *(float2*)&h_out[(size_t)rank[b] * HH + j0] = o;
    }
}

// ---------------------------------------------------------------------------
extern "C" void kernel_launch(void* const* d_in, const int* in_sizes, int n_in,
                              void* d_out, int out_size, void* d_ws, size_t ws_size,
                              hipStream_t stream) {
    const float* x    = (const float*)d_in[0];
    const float* Wp   = (const float*)d_in[1];
    const float* bp   = (const float*)d_in[2];
    const float* Wih0 = (const float*)d_in[3];
    const float* Whh0 = (const float*)d_in[4];
    const float* bih0 = (const float*)d_in[5];
    const float* bhh0 = (const float*)d_in[6];
    const float* Wih1 = (const float*)d_in[7];
    const float* Whh1 = (const float*)d_in[8];
    const float* bih1 = (const float*)d_in[9];
    const float* bhh1 = (const float*)d_in[10];
    float* out = (float*)d_out;

    // workspace: [len 128 int][rank 128 int] ... 4KB ... proj/h1 (64MB), xg (192MB)
    int* len  = (int*)d_ws;
    int* rank = len + 128;
    float* proj = (float*)((char*)d_ws + 4096);                  // [B*S, H]  reused as h1
    float* xgb  = proj + (size_t)BB * SS * HH;                   // [B*S, 3H]

    // 1) lengths + rank
    zero_len_kernel<<<1, 128, 0, stream>>>(len);
    lengths_kernel<<<(BB * SS) / 4, 256, 0, stream>>>(x, len);
    rank_kernel<<<1, 128, 0, stream>>>(len, rank);

    // 2) proj = x @ Wp^T + bp       [131072,512] x [128,512]^T
    gemm_mfma<<<dim3(BB * SS / 64, 1), 256, 0, stream>>>(x, Wp, bp, proj,
                                                         BB * SS, HH, FF);
    // 3) xg0 = proj @ Wih0^T + bih0 [131072,128] x [384,128]^T
    gemm_mfma<<<dim3(BB * SS / 64, 3), 256, 0, stream>>>(proj, Wih0, bih0, xgb,
                                                         BB * SS, G3, HH);
    // 4) layer-1 recurrence -> h1 (into proj region; proj is dead now)
    gru_rec<0><<<BB, 256, 0, stream>>>(xgb, Whh0, bhh0, proj, len, rank);

    // 5) xg1 = h1 @ Wih1^T + bih1 (overwrite xg region)
    gemm_mfma<<<dim3(BB * SS / 64, 3), 256, 0, stream>>>(proj, Wih1, bih1, xgb,
                                                         BB * SS, G3, HH);
    // 6) layer-2 recurrence + masked mean -> out at sorted rank
    gru_rec<1><<<BB, 256, 0, stream>>>(xgb, Whh1, bhh1, out, len, rank);
}

// Round 12
// 2187.948 us; speedup vs baseline: 1.2370x; 1.2370x over previous
//
#include <hip/hip_runtime.h>
#include <hip/hip_bf16.h>

// Sizes fixed by the problem
#define BB 128
#define SS 1024
#define FF 512
#define HH 128
#define G3 384   // 3*H

typedef __attribute__((ext_vector_type(8))) short bf16x8;
typedef __attribute__((ext_vector_type(4))) float f32x4;
typedef _Float16 half2_t __attribute__((ext_vector_type(2)));

// ---------------------------------------------------------------------------
// lengths: len[b] = #rows t with sum_f x[b,t,f] != 0
// ---------------------------------------------------------------------------
__global__ void zero_len_kernel(int* len) { len[threadIdx.x] = 0; }

__global__ void lengths_kernel(const float* __restrict__ x, int* __restrict__ len) {
    int wave = threadIdx.x >> 6;
    int lane = threadIdx.x & 63;
    long row = (long)blockIdx.x * 4 + wave;   // 0 .. 131071
    const float4* p = (const float4*)&x[row * FF + lane * 8];
    float4 v0 = p[0], v1 = p[1];
    float s = v0.x + v0.y + v0.z + v0.w + v1.x + v1.y + v1.z + v1.w;
    #pragma unroll
    for (int off = 32; off > 0; off >>= 1) s += __shfl_down(s, off, 64);
    if (lane == 0 && s != 0.0f) atomicAdd(&len[row >> 10], 1);
}

__global__ void rank_kernel(const int* __restrict__ len, int* __restrict__ rank) {
    int i = threadIdx.x;
    int li = len[i];
    int r = 0;
    for (int jj = 0; jj < BB; jj++) {
        int lj = len[jj];
        if (lj > li || (lj == li && jj < i)) r++;
    }
    rank[i] = r;
}

// ---------------------------------------------------------------------------
// bf16 split helpers (RTN-even rounding; no NaN/inf in this data)
// ---------------------------------------------------------------------------
__device__ __forceinline__ short bf_hi(float w, float& hf) {
    unsigned u = __builtin_bit_cast(unsigned, w);
    unsigned r = (u + 0x7FFFu + ((u >> 16) & 1u)) & 0xFFFF0000u;
    hf = __builtin_bit_cast(float, r);
    return (short)(r >> 16);
}
__device__ __forceinline__ short bf_rn(float w) {
    unsigned u = __builtin_bit_cast(unsigned, w);
    unsigned r = u + 0x7FFFu + ((u >> 16) & 1u);
    return (short)(r >> 16);
}

// ---------------------------------------------------------------------------
// Split-bf16 MFMA GEMM: C[M,N] = A[M,K] @ W[N,K]^T + bias[N]
// (unchanged from round 6; 3-pass hh+hl+lh split -> fp32-grade accuracy)
// ---------------------------------------------------------------------------
__global__ __launch_bounds__(256) void gemm_mfma(
    const float* __restrict__ A, const float* __restrict__ W,
    const float* __restrict__ bias, float* __restrict__ C,
    int M, int N, int K)
{
    const int tid  = threadIdx.x;
    const int wvid = tid >> 6;
    const int lane = tid & 63;
    const int m0   = blockIdx.x * 64 + wvid * 16;
    const int n0   = blockIdx.y * 128;
    const int KS   = K >> 5;

    __shared__ __align__(16) short sh[2][8][64][8];   // 16KB

    f32x4 acc[8];
    #pragma unroll
    for (int i = 0; i < 8; i++) acc[i] = (f32x4){0.f, 0.f, 0.f, 0.f};

    const int arow = m0 + (lane & 15);
    const int koff = (lane >> 4) << 3;

    for (int ks = 0; ks < KS; ks++) {
        __syncthreads();
        #pragma unroll
        for (int i = 0; i < 2; i++) {
            int p  = tid + i * 256;
            int nt = p >> 6, ln = p & 63;
            const float* src = &W[(size_t)(n0 + nt * 16 + (ln & 15)) * K
                                  + ks * 32 + ((ln >> 4) << 3)];
            float w8[8];
            *(float4*)&w8[0] = *(const float4*)&src[0];
            *(float4*)&w8[4] = *(const float4*)&src[4];
            short hi8[8], lo8[8];
            #pragma unroll
            for (int e = 0; e < 8; e++) {
                float hf; hi8[e] = bf_hi(w8[e], hf);
                lo8[e] = bf_rn(w8[e] - hf);
            }
            *(bf16x8*)&sh[0][nt][ln][0] = *(bf16x8*)hi8;
            *(bf16x8*)&sh[1][nt][ln][0] = *(bf16x8*)lo8;
        }
        const float* ap = &A[(size_t)arow * K + ks * 32 + koff];
        float av[8];
        *(float4*)&av[0] = *(const float4*)&ap[0];
        *(float4*)&av[4] = *(const float4*)&ap[4];
        short ah[8], al[8];
        #pragma unroll
        for (int e = 0; e < 8; e++) {
            float hf; ah[e] = bf_hi(av[e], hf);
            al[e] = bf_rn(av[e] - hf);
        }
        bf16x8 ahi = *(bf16x8*)ah, alo = *(bf16x8*)al;
        __syncthreads();
        #pragma unroll
        for (int nt = 0; nt < 8; nt++) {
            bf16x8 bhi = *(bf16x8*)&sh[0][nt][lane][0];
            bf16x8 blo = *(bf16x8*)&sh[1][nt][lane][0];
            acc[nt] = __builtin_amdgcn_mfma_f32_16x16x32_bf16(ahi, bhi, acc[nt], 0, 0, 0);
            acc[nt] = __builtin_amdgcn_mfma_f32_16x16x32_bf16(ahi, blo, acc[nt], 0, 0, 0);
            acc[nt] = __builtin_amdgcn_mfma_f32_16x16x32_bf16(alo, bhi, acc[nt], 0, 0, 0);
        }
    }
    const int crow = m0 + ((lane >> 4) << 2);
    const int ccol = n0 + (lane & 15);
    #pragma unroll
    for (int nt = 0; nt < 8; nt++) {
        int col = ccol + nt * 16;
        float bv = bias[col];
        #pragma unroll
        for (int r = 0; r < 4; r++)
            C[(size_t)(crow + r) * N + col] = acc[nt][r] + bv;
    }
}

// ---------------------------------------------------------------------------
// f16 / DPP helpers
// ---------------------------------------------------------------------------
__device__ __forceinline__ float fast_sigmoid(float x) {
    return __builtin_amdgcn_rcpf(1.0f + __expf(-x));
}
__device__ __forceinline__ float fast_tanh(float x) {
    return 1.0f - 2.0f * __builtin_amdgcn_rcpf(1.0f + __expf(2.0f * x));
}
__device__ __forceinline__ half2_t bc16(unsigned u) {
    return __builtin_bit_cast(half2_t, u);
}
__device__ __forceinline__ unsigned pk16(float x, float y) {
    half2_t h; h[0] = (_Float16)x; h[1] = (_Float16)y;
    return __builtin_bit_cast(unsigned, h);
}
__device__ __forceinline__ float fdot2_(half2_t a, half2_t b, float c) {
#if __has_builtin(__builtin_amdgcn_fdot2)
    return __builtin_amdgcn_fdot2(a, b, c, false);
#else
    return c + (float)a[0] * (float)b[0] + (float)a[1] * (float)b[1];
#endif
}
// quad_perm DPP add: x + x[lane ^ XOR] for XOR in {1,2} (VALU pipe, no DS op)
template<int CTRL>
__device__ __forceinline__ float dpp_xor_add(float v) {
    int vi = __builtin_bit_cast(int, v);
    int sw = __builtin_amdgcn_update_dpp(0, vi, CTRL, 0xF, 0xF, true);
    return v + __builtin_bit_cast(float, sw);
}
#define DPP_XOR1 0xB1   // quad_perm [1,0,3,2]
#define DPP_XOR2 0x4E   // quad_perm [2,3,0,1]

// ---------------------------------------------------------------------------
// GRU recurrence, v12 = r8 geometry + r11 physical-AGPR weights + DPP reduce.
// r3-r10: every virtual-register path re-streams 96-192KB weights/step
// (scratch/L2 or LDS, ~1500-1800 cy/step). r11 proved physical AGPRs hold
// (no reload traffic) but died of latency: 256 thr = 1 wave/SIMD, 192
// serialized ops, nothing to hide bubbles. v12: 512 thr (2 waves/SIMD),
// thread (j=tid>>2, kq=tid&3) owns 3 gates x k-slice [kq*32..+32) = 48
// f16-pair words in PHYSICAL a0..a47 (write once, read 1-cy per step).
// Reduction over kq via quad_perm DPP (VALU) instead of shfl (DS pipe).
// ---------------------------------------------------------------------------
#define AW(N) asm volatile("v_accvgpr_write_b32 a" #N ", %0" :: "v"(wt[(N) & 15]) : "a" #N)
#define DOT(N, ACC) do { unsigned _w; \
    asm volatile("v_accvgpr_read_b32 %0, a" #N : "=v"(_w)); \
    ACC = fdot2_(bc16(_w), bc16(hw[(N) & 15]), ACC); } while (0)

template<int FINAL>
__global__ __launch_bounds__(512, 1) void gru_rec(
    const float* __restrict__ xg,    // [B,S,3H]
    const float* __restrict__ Whh,   // [3H,H]
    const float* __restrict__ bhh,   // [3H]
    float* __restrict__ h_out,       // [B,S,H] (FINAL=0) or [B,H] (FINAL=1)
    const int* __restrict__ len,
    const int* __restrict__ rank)
{
    const int b   = blockIdx.x;
    const int tid = threadIdx.x;
    const int j   = tid >> 2;     // 0..127 output row
    const int kq  = tid & 3;      // K-quarter (32 elems = 16 f16 pairs)

    __shared__ __align__(16) _Float16 h16[2][HH];   // f16 hidden for dots
    __shared__ __align__(16) float    h32[2][HH];   // fp32 hidden for writeout

    // ---- one-time: pack weights to f16 pairs into physical a0..a47 ----
    unsigned wt[16];
    { const float* wr = &Whh[(size_t)(0 * HH + j) * HH + kq * 32];
      #pragma unroll
      for (int m = 0; m < 16; m++) wt[m] = pk16(wr[2*m], wr[2*m+1]); }
    AW(0);  AW(1);  AW(2);  AW(3);  AW(4);  AW(5);  AW(6);  AW(7);
    AW(8);  AW(9);  AW(10); AW(11); AW(12); AW(13); AW(14); AW(15);
    { const float* wr = &Whh[(size_t)(1 * HH + j) * HH + kq * 32];
      #pragma unroll
      for (int m = 0; m < 16; m++) wt[m] = pk16(wr[2*m], wr[2*m+1]); }
    AW(16); AW(17); AW(18); AW(19); AW(20); AW(21); AW(22); AW(23);
    AW(24); AW(25); AW(26); AW(27); AW(28); AW(29); AW(30); AW(31);
    { const float* wr = &Whh[(size_t)(2 * HH + j) * HH + kq * 32];
      #pragma unroll
      for (int m = 0; m < 16; m++) wt[m] = pk16(wr[2*m], wr[2*m+1]); }
    AW(32); AW(33); AW(34); AW(35); AW(36); AW(37); AW(38); AW(39);
    AW(40); AW(41); AW(42); AW(43); AW(44); AW(45); AW(46); AW(47);

    float b_r = 0.f, b_z = 0.f, b_n = 0.f;
    if (kq == 0) { b_r = bhh[j]; b_z = bhh[HH + j]; b_n = bhh[2 * HH + j]; }
    const float* xgb = xg + (size_t)b * SS * G3;

    if (tid < HH) { h16[0][tid] = (_Float16)0.f; h32[0][tid] = 0.f; }
    float hprev = 0.0f, osum = 0.0f;
    const int L = FINAL ? len[b] : 0;

    float xr = 0.f, xz = 0.f, xn = 0.f;
    if (kq == 0) { xr = xgb[j]; xz = xgb[HH + j]; xn = xgb[2 * HH + j]; }
    __syncthreads();

    for (int t = 0; t < SS; t++) {
        const int cb = t & 1, nb = (t + 1) & 1;

        // lagged coalesced global write of h_{t-1} (wave 1)
        if (!FINAL && t > 0 && tid >= 64 && tid < 96) {
            int c = tid - 64;
            float4 hv = ((const float4*)h32[cb])[c];
            *(float4*)&h_out[((size_t)b * SS + (t - 1)) * HH + c * 4] = hv;
        }
        // prefetch xg for t+1
        float nxr = 0.f, nxz = 0.f, nxn = 0.f;
        if (kq == 0 && t + 1 < SS) {
            const float* p = xgb + (size_t)(t + 1) * G3;
            nxr = p[j]; nxz = p[HH + j]; nxn = p[2 * HH + j];
        }
        // h slice: 32 f16 = 4 x b128 (same-address broadcast within kq group)
        const uint4* hp = (const uint4*)&h16[cb][kq * 32];
        uint4 q0 = hp[0], q1 = hp[1], q2 = hp[2], q3 = hp[3];
        unsigned hw[16] = {q0.x,q0.y,q0.z,q0.w, q1.x,q1.y,q1.z,q1.w,
                           q2.x,q2.y,q2.z,q2.w, q3.x,q3.y,q3.z,q3.w};

        float aA, aB;
        // gate r: a0..a15
        aA = 0.f; aB = 0.f;
        DOT(0,aA);  DOT(1,aB);  DOT(2,aA);  DOT(3,aB);
        DOT(4,aA);  DOT(5,aB);  DOT(6,aA);  DOT(7,aB);
        DOT(8,aA);  DOT(9,aB);  DOT(10,aA); DOT(11,aB);
        DOT(12,aA); DOT(13,aB); DOT(14,aA); DOT(15,aB);
        float s0 = aA + aB;
        // gate z: a16..a31
        aA = 0.f; aB = 0.f;
        DOT(16,aA); DOT(17,aB); DOT(18,aA); DOT(19,aB);
        DOT(20,aA); DOT(21,aB); DOT(22,aA); DOT(23,aB);
        DOT(24,aA); DOT(25,aB); DOT(26,aA); DOT(27,aB);
        DOT(28,aA); DOT(29,aB); DOT(30,aA); DOT(31,aB);
        float s1 = aA + aB;
        // gate n: a32..a47
        aA = 0.f; aB = 0.f;
        DOT(32,aA); DOT(33,aB); DOT(34,aA); DOT(35,aB);
        DOT(36,aA); DOT(37,aB); DOT(38,aA); DOT(39,aB);
        DOT(40,aA); DOT(41,aB); DOT(42,aA); DOT(43,aB);
        DOT(44,aA); DOT(45,aB); DOT(46,aA); DOT(47,aB);
        float s2 = aA + aB;

        // reduce over kq (lane bits 0-1) via quad_perm DPP — VALU pipe
        s0 = dpp_xor_add<DPP_XOR1>(s0); s0 = dpp_xor_add<DPP_XOR2>(s0);
        s1 = dpp_xor_add<DPP_XOR1>(s1); s1 = dpp_xor_add<DPP_XOR2>(s1);
        s2 = dpp_xor_add<DPP_XOR1>(s2); s2 = dpp_xor_add<DPP_XOR2>(s2);

        if (kq == 0) {
            float r = fast_sigmoid(xr + s0 + b_r);
            float z = fast_sigmoid(xz + s1 + b_z);
            float n = fast_tanh(xn + r * (s2 + b_n));
            float h = (1.0f - z) * n + z * hprev;
            hprev = h;
            h16[nb][j] = (_Float16)h;
            h32[nb][j] = h;
            if (FINAL) { if (t < L) osum += h; }
        }
        xr = nxr; xz = nxz; xn = nxn;
        __syncthreads();
    }
    if (!FINAL && tid >= 64 && tid < 96) {
        int c = tid - 64;
        float4 hv = ((const float4*)h32[SS & 1])[c];
        *(float4*)&h_out[((size_t)b * SS + (SS - 1)) * HH + c * 4] = hv;
    }
    if (FINAL && kq == 0) {
        h_out[(size_t)rank[b] * HH + j] = osum * (1.0f / (float)SS);
    }
}

// ---------------------------------------------------------------------------
extern "C" void kernel_launch(void* const* d_in, const int* in_sizes, int n_in,
                              void* d_out, int out_size, void* d_ws, size_t ws_size,
                              hipStream_t stream) {
    const float* x    = (const float*)d_in[0];
    const float* Wp   = (const float*)d_in[1];
    const float* bp   = (const float*)d_in[2];
    const float* Wih0 = (const float*)d_in[3];
    const float* Whh0 = (const float*)d_in[4];
    const float* bih0 = (const float*)d_in[5];
    const float* bhh0 = (const float*)d_in[6];
    const float* Wih1 = (const float*)d_in[7];
    const float* Whh1 = (const float*)d_in[8];
    const float* bih1 = (const float*)d_in[9];
    const float* bhh1 = (const float*)d_in[10];
    float* out = (float*)d_out;

    // workspace: [len 128 int][rank 128 int] ... 4KB ... proj/h1 (64MB), xg (192MB)
    int* len  = (int*)d_ws;
    int* rank = len + 128;
    float* proj = (float*)((char*)d_ws + 4096);                  // [B*S, H]  reused as h1
    float* xgb  = proj + (size_t)BB * SS * HH;                   // [B*S, 3H]

    // 1) lengths + rank
    zero_len_kernel<<<1, 128, 0, stream>>>(len);
    lengths_kernel<<<(BB * SS) / 4, 256, 0, stream>>>(x, len);
    rank_kernel<<<1, 128, 0, stream>>>(len, rank);

    // 2) proj = x @ Wp^T + bp       [131072,512] x [128,512]^T
    gemm_mfma<<<dim3(BB * SS / 64, 1), 256, 0, stream>>>(x, Wp, bp, proj,
                                                         BB * SS, HH, FF);
    // 3) xg0 = proj @ Wih0^T + bih0 [131072,128] x [384,128]^T
    gemm_mfma<<<dim3(BB * SS / 64, 3), 256, 0, stream>>>(proj, Wih0, bih0, xgb,
                                                         BB * SS, G3, HH);
    // 4) layer-1 recurrence -> h1 (into proj region; proj is dead now)
    gru_rec<0><<<BB, 512, 0, stream>>>(xgb, Whh0, bhh0, proj, len, rank);

    // 5) xg1 = h1 @ Wih1^T + bih1 (overwrite xg region)
    gemm_mfma<<<dim3(BB * SS / 64, 3), 256, 0, stream>>>(proj, Wih1, bih1, xgb,
                                                         BB * SS, G3, HH);
    // 6) layer-2 recurrence + masked mean -> out at sorted rank
    gru_rec<1><<<BB, 512, 0, stream>>>(xgb, Whh1, bhh1, out, len, rank);
}